// Round 8
// baseline (1022.440 us; speedup 1.0000x reference)
//
#include <hip/hip_runtime.h>
#include <cstdint>
#include <cstddef>

#define BB 16
#define NN 4096
#define CC 64
#define MM 1024
#define KK 64
#define HH 128
#define NEGV -1.0e30f

#define FTH 256   // fps threads per block (4 waves, 1 per SIMD)
#define FPT 16    // points per thread (FTH*FPT == NN)

#define KC1 96    // layer-1 K dim padded (67 -> 96)
#define SA 104    // LDS stride of feat planes (elements; bank-tiled, 16B-aligned)
#define SH 136    // LDS stride of h1 planes

typedef __attribute__((ext_vector_type(8))) short bf16x8;   // 8 bf16 = 4 VGPRs
typedef __attribute__((ext_vector_type(4))) float f32x4;
typedef __attribute__((ext_vector_type(2))) float f32x2;
typedef __attribute__((ext_vector_type(2))) unsigned long long u64x2;

// round-to-nearest-even f32 -> bf16 (as u16 in low bits)
__device__ __forceinline__ unsigned int f2bf(float f) {
  unsigned int u = __float_as_uint(f);
  return (u + 0x7fffu + ((u >> 16) & 1u)) >> 16;
}
// split f into bf16 hi + bf16 lo with f ~= hi + lo to ~2^-18 rel
__device__ __forceinline__ void split2(float f, unsigned int& h, unsigned int& l) {
  h = f2bf(f);
  float hf = __uint_as_float(h << 16);
  l = f2bf(f - hf);
}

// DPP-moved copy: lanes with no valid source (or outside row mask) keep self.
template <int CTRL, int RM>
__device__ __forceinline__ int dpp_mov(int v) {
  return __builtin_amdgcn_update_dpp(v, v, CTRL, RM, 0xf, false);
}
// value-only wave-max chain step (compiler fuses mov_dpp into v_max_f32)
template <int CTRL, int RM>
__device__ __forceinline__ void dpp_fmax(float& v) {
  v = fmaxf(v, __int_as_float(dpp_mov<CTRL, RM>(__float_as_int(v))));
}
template <int CTRL, int RM>
__device__ __forceinline__ void dpp_umin(unsigned int& v) {
  unsigned int o = (unsigned int)dpp_mov<CTRL, RM>((int)v);
  v = o < v ? o : v;
}

// ---------------------------------------------------------------------------
// Stage 1: farthest point sampling. One block per batch, 256 threads (4
// waves = 1/SIMD; R6/R7 showed per-wave reduce overhead replicates per
// wave). 16 pts/thread as 8 float2 pairs -> packed v_pk_{add,mul}_f32
// (bit-identical per component, contract still off). Argmax tracking in 4
// independent chains (ascending j blocks, strict > merge = first
// occurrence). Wave reduce: 6-step v_max_f32-DPP value chain -> readlane63
// -> tie mask (bv==wmax) -> v_min_u32-DPP index chain -> lane63 packs
// (wmax, ~min_bi) u64; cross-wave = 3 u64 maxes. All reductions exact
// (max/min order-free, unique indices, numpy first-occurrence preserved).
// ---------------------------------------------------------------------------
__global__ __launch_bounds__(FTH) void fps_kernel(const float* __restrict__ pos,
                                                  float* __restrict__ pos_s_ws,
                                                  float* __restrict__ pos_s_out) {
#pragma clang fp contract(off)
  const int b = blockIdx.x;
  const int t = threadIdx.x;
  const int lane = t & 63;
  const int wave = t >> 6;          // 0..3
  __shared__ __attribute__((aligned(16))) float4 P4[NN];
  __shared__ float SXa[MM], SYa[MM], SZa[MM];
  __shared__ __attribute__((aligned(16))) unsigned long long cand[2][FTH / 64];
  const float* pb = pos + (size_t)b * NN * 3;
  f32x2 px2[FPT / 2], py2[FPT / 2], pz2[FPT / 2], dd2[FPT / 2];
#pragma unroll
  for (int p = 0; p < FPT / 2; ++p) {
    int i0 = t + (2 * p) * FTH;
    int i1 = t + (2 * p + 1) * FTH;
    float x0 = pb[i0 * 3 + 0], y0 = pb[i0 * 3 + 1], z0 = pb[i0 * 3 + 2];
    float x1 = pb[i1 * 3 + 0], y1 = pb[i1 * 3 + 1], z1 = pb[i1 * 3 + 2];
    P4[i0] = make_float4(x0, y0, z0, 0.0f);
    P4[i1] = make_float4(x1, y1, z1, 0.0f);
    px2[p] = (f32x2){x0, x1}; py2[p] = (f32x2){y0, y1}; pz2[p] = (f32x2){z0, z1};
    dd2[p] = (f32x2){3.4028234663852886e38f, 3.4028234663852886e38f};
  }
  __syncthreads();
  float4 c4 = P4[0];
  float sx = c4.x, sy = c4.y, sz = c4.z;
  if (t == 0) { SXa[0] = sx; SYa[0] = sy; SZa[0] = sz; }
  const unsigned int BIGIDX = 0x7fffffffu;

  for (int m = 1; m < MM; ++m) {
    f32x2 sx2 = (f32x2){sx, sx}, sy2 = (f32x2){sy, sy}, sz2 = (f32x2){sz, sz};
    float bv[4]; int jb[4];
#pragma unroll
    for (int c = 0; c < 4; ++c) { bv[c] = -1.0f; jb[c] = 0; }
#pragma unroll
    for (int c = 0; c < 4; ++c) {
#pragma unroll
      for (int pp = 0; pp < 2; ++pp) {
        int p = c * 2 + pp;
        f32x2 dx = px2[p] - sx2, dy = py2[p] - sy2, dz = pz2[p] - sz2;
        f32x2 d2 = (dx * dx + dy * dy) + dz * dz;   // pk ops, no FMA (pragma)
        f32x2 nd;
        nd.x = fminf(dd2[p].x, d2.x);
        nd.y = fminf(dd2[p].y, d2.y);
        dd2[p] = nd;
        if (nd.x > bv[c]) { bv[c] = nd.x; jb[c] = 2 * p; }       // ascending j
        if (nd.y > bv[c]) { bv[c] = nd.y; jb[c] = 2 * p + 1; }
      }
    }
    // merge 4 chains (chain c covers j in [4c,4c+4): strict > keeps first)
    float BV = bv[0]; int JB = jb[0];
#pragma unroll
    for (int c = 1; c < 4; ++c)
      if (bv[c] > BV) { BV = bv[c]; JB = jb[c]; }
    // wave value-max chain -> lane63
    float vm = BV;
    dpp_fmax<0x111, 0xf>(vm);   // row_shr:1
    dpp_fmax<0x112, 0xf>(vm);   // row_shr:2
    dpp_fmax<0x114, 0xf>(vm);   // row_shr:4
    dpp_fmax<0x118, 0xf>(vm);   // row_shr:8
    dpp_fmax<0x142, 0xa>(vm);   // row_bcast15
    dpp_fmax<0x143, 0xc>(vm);   // row_bcast31 -> lane63 = wave max
    unsigned int wmax = (unsigned int)__builtin_amdgcn_readlane(
        __float_as_int(vm), 63);
    // tie -> min block index over tied lanes (numpy first-occurrence)
    unsigned int bi = (unsigned int)(t + (JB << 8));
    unsigned int mi = (__float_as_uint(BV) == wmax) ? bi : BIGIDX;
    dpp_umin<0x111, 0xf>(mi);
    dpp_umin<0x112, 0xf>(mi);
    dpp_umin<0x114, 0xf>(mi);
    dpp_umin<0x118, 0xf>(mi);
    dpp_umin<0x142, 0xa>(mi);
    dpp_umin<0x143, 0xc>(mi);   // lane63 = wave min index
    if (lane == 63)
      cand[m & 1][wave] = ((unsigned long long)wmax << 32) | (~mi);
    __syncthreads();
    u64x2 c01 = *(const u64x2*)&cand[m & 1][0];
    u64x2 c23 = *(const u64x2*)&cand[m & 1][2];
    unsigned long long b0 = c01.x > c01.y ? c01.x : c01.y;
    unsigned long long b1 = c23.x > c23.y ? c23.x : c23.y;
    unsigned long long best = b0 > b1 ? b0 : b1;
    int fi = (int)(~(unsigned int)(best & 0xffffffffull));
    float4 w4 = P4[fi];              // broadcast ds_read_b128
    sx = w4.x; sy = w4.y; sz = w4.z;
    if (t == 0) { SXa[m] = sx; SYa[m] = sy; SZa[m] = sz; }
  }
  __syncthreads();
  for (int i = t; i < MM; i += FTH) {
    size_t o = ((size_t)b * MM + i) * 3;
    float ox = SXa[i], oy = SYa[i], oz = SZa[i];
    pos_s_ws[o + 0] = ox; pos_s_ws[o + 1] = oy; pos_s_ws[o + 2] = oz;
    pos_s_out[o + 0] = ox; pos_s_out[o + 1] = oy; pos_s_out[o + 2] = oz;
  }
}

// ---------------------------------------------------------------------------
// Stage 2a: |p|^2 per point, exact order (x^2+y^2)+z^2, no FMA.
// ---------------------------------------------------------------------------
__global__ __launch_bounds__(256) void pn_kernel(const float* __restrict__ pos,
                                                 float* __restrict__ pn) {
#pragma clang fp contract(off)
  int i = blockIdx.x * 256 + threadIdx.x;
  if (i < BB * NN) {
    float x = pos[(size_t)i * 3 + 0];
    float y = pos[(size_t)i * 3 + 1];
    float z = pos[(size_t)i * 3 + 2];
    pn[i] = (x * x + y * y) + z * z;
  }
}

// ---------------------------------------------------------------------------
// Stage 2b: radius ball query (exact einsum FMA-chain dot; see R1 notes).
// ---------------------------------------------------------------------------
__global__ __launch_bounds__(256) void ballq_kernel(const float* __restrict__ pos,
                                                    const float* __restrict__ pn,
                                                    const float* __restrict__ pos_s,
                                                    int* __restrict__ nbr,
                                                    int* __restrict__ cntArr) {
#pragma clang fp contract(off)
  const int wave = threadIdx.x >> 6;
  const int lane = threadIdx.x & 63;
  const int cid = blockIdx.x * 4 + wave;
  const int b = cid >> 10;
  const float sx = pos_s[(size_t)cid * 3 + 0];
  const float sy = pos_s[(size_t)cid * 3 + 1];
  const float sz = pos_s[(size_t)cid * 3 + 2];
  const float sn = (sx * sx + sy * sy) + sz * sz;
  const float* pb = pos + (size_t)b * NN * 3;
  const float* pnb = pn + (size_t)b * NN;
  int count = 0;
  for (int chunk = 0; chunk < NN / 64 && count < KK; ++chunk) {
    int n = chunk * 64 + lane;
    float x = pb[n * 3 + 0], y = pb[n * 3 + 1], z = pb[n * 3 + 2];
    float dot = __builtin_fmaf(sz, z, __builtin_fmaf(sy, y, sx * x));
    float d2 = (sn + pnb[n]) - 2.0f * dot;
    bool pred = d2 <= 0.04f;
    unsigned long long mask = __ballot(pred);
    int slot = count + (int)__popcll(mask & ((1ull << lane) - 1ull));
    if (pred && slot < KK) nbr[(size_t)cid * KK + slot] = n;
    count += (int)__popcll(mask);
  }
  if (lane == 0) cntArr[cid] = count < KK ? count : KK;
}

// ---------------------------------------------------------------------------
// Weight prep (once): transpose + pad + bf16 hi/lo split, B-fragment layout
// [n][k]. Block n (128 blocks), 128 threads.
// ---------------------------------------------------------------------------
__global__ __launch_bounds__(128) void wprep_kernel(
    const float* __restrict__ W1, const float* __restrict__ W2,
    unsigned short* __restrict__ W1Th, unsigned short* __restrict__ W1Tl,
    unsigned short* __restrict__ W2Th, unsigned short* __restrict__ W2Tl) {
  const int n = blockIdx.x, t = threadIdx.x;
  if (t < KC1) {
    float v = (t < 67) ? W1[(size_t)t * HH + n] : 0.0f;
    unsigned int h, l; split2(v, h, l);
    W1Th[n * KC1 + t] = (unsigned short)h;
    W1Tl[n * KC1 + t] = (unsigned short)l;
  }
  {
    float v = W2[(size_t)t * HH + n];
    unsigned int h, l; split2(v, h, l);
    W2Th[n * HH + t] = (unsigned short)h;
    W2Tl[n * HH + t] = (unsigned short)l;
  }
}

// ---------------------------------------------------------------------------
// Stage 3+4: gather -> split-bf16 MFMA MLP -> masked max. One block/center,
// 4 waves; wave w owns output columns [w*32, w*32+32). 3-term split MFMA
// (Ah*Bh + Al*Bh + Ah*Bl) gives ~2^-18 rel error vs fp32.
// Fragment maps (verified m89/m91/m120): A[m=lane&15][k=quad*8+j],
// B[k=quad*8+j][n=lane&15], D[row=quad*4+reg][col=lane&15].
// ---------------------------------------------------------------------------
__global__ __launch_bounds__(256) void mlp_kernel(
    const float* __restrict__ x, const float* __restrict__ pos,
    const float* __restrict__ pos_s, const int* __restrict__ nbr,
    const int* __restrict__ cntArr,
    const unsigned short* __restrict__ W1Th, const unsigned short* __restrict__ W1Tl,
    const unsigned short* __restrict__ W2Th, const unsigned short* __restrict__ W2Tl,
    const float* __restrict__ b1, const float* __restrict__ b2,
    float* __restrict__ out) {
  __shared__ __attribute__((aligned(16))) unsigned short Ah[64 * SA];
  __shared__ __attribute__((aligned(16))) unsigned short Al[64 * SA];
  __shared__ __attribute__((aligned(16))) unsigned short Hh[64 * SH];
  __shared__ __attribute__((aligned(16))) unsigned short Hl[64 * SH];
  __shared__ int nbr_s[KK];
  __shared__ float ctr[3];
  __shared__ int cnt_s;
  const int cid = blockIdx.x;
  const int b = cid >> 10;
  const int t = threadIdx.x;
  const int lane = t & 63, wv = t >> 6;
  const int r = lane & 15, q = lane >> 4;
  const int wbase = wv * 32;

  if (t < KK) nbr_s[t] = nbr[(size_t)cid * KK + t];
  if (t < 3)  ctr[t] = pos_s[(size_t)cid * 3 + t];
  if (t == 0) cnt_s = cntArr[cid];
  __syncthreads();
  const int cnt = cnt_s;

  // ---- gather + hi/lo split into LDS feat planes ----
  {
    const int kn = t >> 2, p = t & 3;   // neighbor row, channel quarter
    float vals[16];
    float d0 = 0.0f, d1 = 0.0f, d2v = 0.0f;
    if (kn < cnt) {
      int n = nbr_s[kn];
      const float* xp = x + ((size_t)b * NN + n) * CC + p * 16;
#pragma unroll
      for (int i = 0; i < 4; ++i) {
        float4 v = ((const float4*)xp)[i];
        vals[i * 4 + 0] = v.x; vals[i * 4 + 1] = v.y;
        vals[i * 4 + 2] = v.z; vals[i * 4 + 3] = v.w;
      }
      if (p == 0) {
        const float* pp = pos + ((size_t)b * NN + n) * 3;
        d0 = pp[0] - ctr[0]; d1 = pp[1] - ctr[1]; d2v = pp[2] - ctr[2];
      }
    } else {
#pragma unroll
      for (int i = 0; i < 16; ++i) vals[i] = 0.0f;
    }
#pragma unroll
    for (int j = 0; j < 16; j += 2) {
      unsigned int h0, l0, h1, l1;
      split2(vals[j], h0, l0);
      split2(vals[j + 1], h1, l1);
      int c = p * 16 + j;
      *(unsigned int*)&Ah[kn * SA + c] = h0 | (h1 << 16);
      *(unsigned int*)&Al[kn * SA + c] = l0 | (l1 << 16);
    }
    if (p == 0) {
      unsigned int h0, l0, h1, l1, h2, l2;
      split2(d0, h0, l0); split2(d1, h1, l1); split2(d2v, h2, l2);
      *(unsigned int*)&Ah[kn * SA + 64] = h0 | (h1 << 16);
      *(unsigned int*)&Al[kn * SA + 64] = l0 | (l1 << 16);
      *(unsigned int*)&Ah[kn * SA + 66] = h2;        // c=67 zero
      *(unsigned int*)&Al[kn * SA + 66] = l2;
    } else if (p == 1) {
#pragma unroll
      for (int c = 68; c < 80; c += 2) {
        *(unsigned int*)&Ah[kn * SA + c] = 0u;
        *(unsigned int*)&Al[kn * SA + c] = 0u;
      }
    } else if (p == 2) {
#pragma unroll
      for (int c = 80; c < 96; c += 2) {
        *(unsigned int*)&Ah[kn * SA + c] = 0u;
        *(unsigned int*)&Al[kn * SA + c] = 0u;
      }
    }
  }
  __syncthreads();

  f32x4 acc[4][2];
#pragma unroll
  for (int mt = 0; mt < 4; ++mt)
#pragma unroll
    for (int nt = 0; nt < 2; ++nt) acc[mt][nt] = (f32x4)0.0f;

  // ---- layer 1: feat[64x96] @ W1T -> h1[64x128] ----
#pragma unroll
  for (int kc = 0; kc < 3; ++kc) {
    bf16x8 bh[2], bl[2];
#pragma unroll
    for (int nt = 0; nt < 2; ++nt) {
      int o = (wbase + nt * 16 + r) * KC1 + kc * 32 + q * 8;
      bh[nt] = *(const bf16x8*)(W1Th + o);
      bl[nt] = *(const bf16x8*)(W1Tl + o);
    }
#pragma unroll
    for (int mt = 0; mt < 4; ++mt) {
      int o = (mt * 16 + r) * SA + kc * 32 + q * 8;
      bf16x8 ah = *(const bf16x8*)&Ah[o];
      bf16x8 al = *(const bf16x8*)&Al[o];
#pragma unroll
      for (int nt = 0; nt < 2; ++nt) {
        acc[mt][nt] = __builtin_amdgcn_mfma_f32_16x16x32_bf16(ah, bh[nt], acc[mt][nt], 0, 0, 0);
        acc[mt][nt] = __builtin_amdgcn_mfma_f32_16x16x32_bf16(al, bh[nt], acc[mt][nt], 0, 0, 0);
        acc[mt][nt] = __builtin_amdgcn_mfma_f32_16x16x32_bf16(ah, bl[nt], acc[mt][nt], 0, 0, 0);
      }
    }
  }

  // ---- bias + relu + split into h1 planes ----
  {
    float b1v[2] = { b1[wbase + r], b1[wbase + 16 + r] };
#pragma unroll
    for (int mt = 0; mt < 4; ++mt)
#pragma unroll
      for (int nt = 0; nt < 2; ++nt)
#pragma unroll
        for (int i = 0; i < 4; ++i) {
          int m = mt * 16 + q * 4 + i;
          int n = wbase + nt * 16 + r;
          float v = fmaxf(acc[mt][nt][i] + b1v[nt], 0.0f);
          unsigned int h, l; split2(v, h, l);
          Hh[m * SH + n] = (unsigned short)h;
          Hl[m * SH + n] = (unsigned short)l;
        }
  }
  __syncthreads();

  // ---- layer 2: h1[64x128] @ W2T ----
#pragma unroll
  for (int mt = 0; mt < 4; ++mt)
#pragma unroll
    for (int nt = 0; nt < 2; ++nt) acc[mt][nt] = (f32x4)0.0f;
#pragma unroll
  for (int kc = 0; kc < 4; ++kc) {
    bf16x8 bh[2], bl[2];
#pragma unroll
    for (int nt = 0; nt < 2; ++nt) {
      int o = (wbase + nt * 16 + r) * HH + kc * 32 + q * 8;
      bh[nt] = *(const bf16x8*)(W2Th + o);
      bl[nt] = *(const bf16x8*)(W2Tl + o);
    }
#pragma unroll
    for (int mt = 0; mt < 4; ++mt) {
      int o = (mt * 16 + r) * SH + kc * 32 + q * 8;
      bf16x8 ah = *(const bf16x8*)&Hh[o];
      bf16x8 al = *(const bf16x8*)&Hl[o];
#pragma unroll
      for (int nt = 0; nt < 2; ++nt) {
        acc[mt][nt] = __builtin_amdgcn_mfma_f32_16x16x32_bf16(ah, bh[nt], acc[mt][nt], 0, 0, 0);
        acc[mt][nt] = __builtin_amdgcn_mfma_f32_16x16x32_bf16(al, bh[nt], acc[mt][nt], 0, 0, 0);
        acc[mt][nt] = __builtin_amdgcn_mfma_f32_16x16x32_bf16(ah, bl[nt], acc[mt][nt], 0, 0, 0);
      }
    }
  }

  // ---- bias + relu + masked max over valid rows, write out ----
  {
    float b2v[2] = { b2[wbase + r], b2[wbase + 16 + r] };
#pragma unroll
    for (int nt = 0; nt < 2; ++nt) {
      float vmax = NEGV;
#pragma unroll
      for (int mt = 0; mt < 4; ++mt)
#pragma unroll
        for (int i = 0; i < 4; ++i) {
          int m = mt * 16 + q * 4 + i;
          float v = fmaxf(acc[mt][nt][i] + b2v[nt], 0.0f);
          if (m < cnt) vmax = fmaxf(vmax, v);
        }
      vmax = fmaxf(vmax, __shfl_xor(vmax, 16, 64));
      vmax = fmaxf(vmax, __shfl_xor(vmax, 32, 64));
      if (q == 0)
        out[(size_t)cid * HH + wbase + nt * 16 + r] = (cnt > 0) ? vmax : 0.0f;
    }
  }
}

// ---------------------------------------------------------------------------
extern "C" void kernel_launch(void* const* d_in, const int* in_sizes, int n_in,
                              void* d_out, int out_size, void* d_ws, size_t ws_size,
                              hipStream_t stream) {
  const float* x   = (const float*)d_in[0];
  const float* pos = (const float*)d_in[1];
  const float* W1  = (const float*)d_in[2];
  const float* b1  = (const float*)d_in[3];
  const float* W2  = (const float*)d_in[4];
  const float* b2  = (const float*)d_in[5];
  float* out = (float*)d_out;
  float* pos_s_out = out + (size_t)BB * MM * HH;

  char* ws = (char*)d_ws;
  float* pos_s_ws = (float*)(ws);                       // 196608 B
  float* pn       = (float*)(ws + 196608);              // 262144 B
  int*   nbr      = (int*)  (ws + 458752);              // 4194304 B
  int*   cnt      = (int*)  (ws + 4653056);             // 65536 B
  unsigned short* W1Th = (unsigned short*)(ws + 4718592);  // 24576 B
  unsigned short* W1Tl = (unsigned short*)(ws + 4743168);  // 24576 B
  unsigned short* W2Th = (unsigned short*)(ws + 4767744);  // 32768 B
  unsigned short* W2Tl = (unsigned short*)(ws + 4800512);  // 32768 B

  wprep_kernel<<<HH, 128, 0, stream>>>(W1, W2, W1Th, W1Tl, W2Th, W2Tl);
  fps_kernel<<<BB, FTH, 0, stream>>>(pos, pos_s_ws, pos_s_out);
  pn_kernel<<<(BB * NN) / 256, 256, 0, stream>>>(pos, pn);
  ballq_kernel<<<(BB * MM) / 4, 256, 0, stream>>>(pos, pn, pos_s_ws, nbr, cnt);
  mlp_kernel<<<BB * MM, 256, 0, stream>>>(x, pos, pos_s_ws, nbr, cnt,
                                          W1Th, W1Tl, W2Th, W2Tl, b1, b2, out);
}

// Round 9
// 950.214 us; speedup vs baseline: 1.0760x; 1.0760x over previous
//
#include <hip/hip_runtime.h>
#include <cstdint>
#include <cstddef>

#define BB 16
#define NN 4096
#define CC 64
#define MM 1024
#define KK 64
#define HH 128
#define NEGV -1.0e30f

#define FTH 256   // fps threads per block (4 waves, 1 per SIMD)
#define FPT 16    // points per thread (FTH*FPT == NN)

#define KC1 96    // layer-1 K dim padded (67 -> 96)
#define SA 104    // LDS stride of feat planes (elements; bank-tiled, 16B-aligned)
#define SH 136    // LDS stride of h1 planes

typedef __attribute__((ext_vector_type(8))) short bf16x8;   // 8 bf16 = 4 VGPRs
typedef __attribute__((ext_vector_type(4))) float f32x4;

// round-to-nearest-even f32 -> bf16 (as u16 in low bits)
__device__ __forceinline__ unsigned int f2bf(float f) {
  unsigned int u = __float_as_uint(f);
  return (u + 0x7fffu + ((u >> 16) & 1u)) >> 16;
}
// split f into bf16 hi + bf16 lo with f ~= hi + lo to ~2^-18 rel
__device__ __forceinline__ void split2(float f, unsigned int& h, unsigned int& l) {
  h = f2bf(f);
  float hf = __uint_as_float(h << 16);
  l = f2bf(f - hf);
}

// one DPP u64-max step: compare with DPP-moved neighbor, keep larger.
// CTRL: 0x111/0x112/0x114/0x118 = row_shr 1/2/4/8, 0x142 = row_bcast15,
// 0x143 = row_bcast31. bound_ctrl=false -> invalid lanes keep old (self).
// (semantics HW-validated in R5: absmax bit-identical to shuffle version)
template <int CTRL, int RM>
__device__ __forceinline__ void dpp_max64(unsigned int& hi, unsigned int& lo) {
  unsigned int shi = (unsigned int)__builtin_amdgcn_update_dpp(
      (int)hi, (int)hi, CTRL, RM, 0xf, false);
  unsigned int slo = (unsigned int)__builtin_amdgcn_update_dpp(
      (int)lo, (int)lo, CTRL, RM, 0xf, false);
  unsigned long long cur = ((unsigned long long)hi << 32) | lo;
  unsigned long long oth = ((unsigned long long)shi << 32) | slo;
  if (oth > cur) { hi = shi; lo = slo; }
}

// ---------------------------------------------------------------------------
// Stage 1: farthest point sampling — EXACT R7 version (best measured 616us;
// R8's packed/min-chain variants regressed: less issue but longer serial
// cross-lane chain). One block per batch, 256 threads (4 waves = 1/SIMD),
// 16 pts/thread. Exact numpy arithmetic: no FMA, (dx*dx+dy*dy)+dz*dz,
// strict > in-loop argmax (first-occurrence), u64 (d2,~idx) keys.
// ---------------------------------------------------------------------------
__global__ __launch_bounds__(FTH) void fps_kernel(const float* __restrict__ pos,
                                                  float* __restrict__ pos_s_ws,
                                                  float* __restrict__ pos_s_out) {
#pragma clang fp contract(off)
  const int b = blockIdx.x;
  const int t = threadIdx.x;
  const int lane = t & 63;
  const int wave = t >> 6;          // 0..3
  __shared__ __attribute__((aligned(16))) float4 P4[NN];
  __shared__ float SXa[MM], SYa[MM], SZa[MM];
  __shared__ unsigned long long cand[2][FTH / 64];
  const float* pb = pos + (size_t)b * NN * 3;
  float px[FPT], py[FPT], pz[FPT], dd[FPT];
#pragma unroll
  for (int j = 0; j < FPT; ++j) {
    int i = t + j * FTH;
    float xx = pb[i * 3 + 0], yy = pb[i * 3 + 1], zz = pb[i * 3 + 2];
    P4[i] = make_float4(xx, yy, zz, 0.0f);
    px[j] = xx; py[j] = yy; pz[j] = zz;
    dd[j] = 3.4028234663852886e38f;   // finfo(float32).max
  }
  __syncthreads();
  float4 c4 = P4[0];
  float sx = c4.x, sy = c4.y, sz = c4.z;
  if (t == 0) { SXa[0] = sx; SYa[0] = sy; SZa[0] = sz; }

  for (int m = 1; m < MM; ++m) {
    float bv = -1.0f;
    int   bi = 0;
#pragma unroll
    for (int j = 0; j < FPT; ++j) {
      float dx = px[j] - sx, dy = py[j] - sy, dz = pz[j] - sz;
      float d2 = (dx * dx + dy * dy) + dz * dz;   // no FMA (pragma)
      float nd = fminf(dd[j], d2);
      dd[j] = nd;
      if (nd > bv) { bv = nd; bi = t + (j << 8); }  // ascending idx: first wins
    }
    // pack (d2, ~idx): d2>=0 so float bits order-preserving; larger key =
    // larger value, ties -> smaller index (numpy first-occurrence)
    unsigned int kh = __float_as_uint(bv);
    unsigned int kl = ~(unsigned int)bi;
    dpp_max64<0x111, 0xf>(kh, kl);   // row_shr:1
    dpp_max64<0x112, 0xf>(kh, kl);   // row_shr:2
    dpp_max64<0x114, 0xf>(kh, kl);   // row_shr:4
    dpp_max64<0x118, 0xf>(kh, kl);   // row_shr:8  -> lane15/31/47/63 row maxes
    dpp_max64<0x142, 0xa>(kh, kl);   // row_bcast15 -> lane31, lane63
    dpp_max64<0x143, 0xc>(kh, kl);   // row_bcast31 -> lane63 = wave max
    if (lane == 63)
      cand[m & 1][wave] = ((unsigned long long)kh << 32) | kl;
    __syncthreads();
    unsigned long long best = cand[m & 1][0];
#pragma unroll
    for (int w = 1; w < FTH / 64; ++w) {
      unsigned long long ok = cand[m & 1][w];
      best = ok > best ? ok : best;
    }
    int fi = (int)(~(unsigned int)(best & 0xffffffffull));
    float4 w4 = P4[fi];              // broadcast ds_read_b128
    sx = w4.x; sy = w4.y; sz = w4.z;
    if (t == 0) { SXa[m] = sx; SYa[m] = sy; SZa[m] = sz; }
  }
  __syncthreads();
  for (int i = t; i < MM; i += FTH) {
    size_t o = ((size_t)b * MM + i) * 3;
    float ox = SXa[i], oy = SYa[i], oz = SZa[i];
    pos_s_ws[o + 0] = ox; pos_s_ws[o + 1] = oy; pos_s_ws[o + 2] = oz;
    pos_s_out[o + 0] = ox; pos_s_out[o + 1] = oy; pos_s_out[o + 2] = oz;
  }
}

// ---------------------------------------------------------------------------
// Stage 2a: |p|^2 per point, exact order (x^2+y^2)+z^2, no FMA.
// ---------------------------------------------------------------------------
__global__ __launch_bounds__(256) void pn_kernel(const float* __restrict__ pos,
                                                 float* __restrict__ pn) {
#pragma clang fp contract(off)
  int i = blockIdx.x * 256 + threadIdx.x;
  if (i < BB * NN) {
    float x = pos[(size_t)i * 3 + 0];
    float y = pos[(size_t)i * 3 + 1];
    float z = pos[(size_t)i * 3 + 2];
    pn[i] = (x * x + y * y) + z * z;
  }
}

// ---------------------------------------------------------------------------
// Stage 2b: radius ball query (exact einsum FMA-chain dot; see R1 notes).
// ---------------------------------------------------------------------------
__global__ __launch_bounds__(256) void ballq_kernel(const float* __restrict__ pos,
                                                    const float* __restrict__ pn,
                                                    const float* __restrict__ pos_s,
                                                    int* __restrict__ nbr,
                                                    int* __restrict__ cntArr) {
#pragma clang fp contract(off)
  const int wave = threadIdx.x >> 6;
  const int lane = threadIdx.x & 63;
  const int cid = blockIdx.x * 4 + wave;
  const int b = cid >> 10;
  const float sx = pos_s[(size_t)cid * 3 + 0];
  const float sy = pos_s[(size_t)cid * 3 + 1];
  const float sz = pos_s[(size_t)cid * 3 + 2];
  const float sn = (sx * sx + sy * sy) + sz * sz;
  const float* pb = pos + (size_t)b * NN * 3;
  const float* pnb = pn + (size_t)b * NN;
  int count = 0;
  for (int chunk = 0; chunk < NN / 64 && count < KK; ++chunk) {
    int n = chunk * 64 + lane;
    float x = pb[n * 3 + 0], y = pb[n * 3 + 1], z = pb[n * 3 + 2];
    float dot = __builtin_fmaf(sz, z, __builtin_fmaf(sy, y, sx * x));
    float d2 = (sn + pnb[n]) - 2.0f * dot;
    bool pred = d2 <= 0.04f;
    unsigned long long mask = __ballot(pred);
    int slot = count + (int)__popcll(mask & ((1ull << lane) - 1ull));
    if (pred && slot < KK) nbr[(size_t)cid * KK + slot] = n;
    count += (int)__popcll(mask);
  }
  if (lane == 0) cntArr[cid] = count < KK ? count : KK;
}

// ---------------------------------------------------------------------------
// Weight prep (once): transpose + pad + bf16 hi/lo split, B-fragment layout
// [n][k]. Block n (128 blocks), 128 threads.
// ---------------------------------------------------------------------------
__global__ __launch_bounds__(128) void wprep_kernel(
    const float* __restrict__ W1, const float* __restrict__ W2,
    unsigned short* __restrict__ W1Th, unsigned short* __restrict__ W1Tl,
    unsigned short* __restrict__ W2Th, unsigned short* __restrict__ W2Tl) {
  const int n = blockIdx.x, t = threadIdx.x;
  if (t < KC1) {
    float v = (t < 67) ? W1[(size_t)t * HH + n] : 0.0f;
    unsigned int h, l; split2(v, h, l);
    W1Th[n * KC1 + t] = (unsigned short)h;
    W1Tl[n * KC1 + t] = (unsigned short)l;
  }
  {
    float v = W2[(size_t)t * HH + n];
    unsigned int h, l; split2(v, h, l);
    W2Th[n * HH + t] = (unsigned short)h;
    W2Tl[n * HH + t] = (unsigned short)l;
  }
}

// ---------------------------------------------------------------------------
// Stage 3+4: gather -> split-bf16 MFMA MLP -> masked max. One block/center,
// 4 waves; wave w owns output columns [w*32, w*32+32). 3-term split MFMA
// (Ah*Bh + Al*Bh + Ah*Bl) ~2^-18 rel error vs fp32.
// R9: LDS occupancy fix — A-planes (26.6KB) and H-planes (34.8KB) alias in
// one 34.8KB union (A fully consumed by last L1 MFMA read; barrier guards
// the overwrite) -> 4 blocks/CU (was 2). nbr/ctr/cnt moved to per-thread
// global loads (L1/L2-cached), removing the init LDS round-trip + barrier.
// Fragment maps (verified m89/m91/m120): A[m=lane&15][k=quad*8+j],
// B[k=quad*8+j][n=lane&15], D[row=quad*4+reg][col=lane&15].
// ---------------------------------------------------------------------------
__global__ __launch_bounds__(256, 4) void mlp_kernel(
    const float* __restrict__ x, const float* __restrict__ pos,
    const float* __restrict__ pos_s, const int* __restrict__ nbr,
    const int* __restrict__ cntArr,
    const unsigned short* __restrict__ W1Th, const unsigned short* __restrict__ W1Tl,
    const unsigned short* __restrict__ W2Th, const unsigned short* __restrict__ W2Tl,
    const float* __restrict__ b1, const float* __restrict__ b2,
    float* __restrict__ out) {
  // union: [Ah 13312B | Al 13312B] aliased with [Hh 17408B | Hl 17408B]
  __shared__ __attribute__((aligned(16))) unsigned char SMEM[64 * SH * 2 * 2];
  unsigned short* Ah = (unsigned short*)SMEM;
  unsigned short* Al = (unsigned short*)(SMEM + 64 * SA * 2);
  unsigned short* Hh = (unsigned short*)SMEM;
  unsigned short* Hl = (unsigned short*)(SMEM + 64 * SH * 2);
  const int cid = blockIdx.x;
  const int b = cid >> 10;
  const int t = threadIdx.x;
  const int lane = t & 63, wv = t >> 6;
  const int r = lane & 15, q = lane >> 4;
  const int wbase = wv * 32;

  const int cnt = cntArr[cid];   // per-thread load, L2-cached

  // ---- gather + hi/lo split into LDS feat planes (no init barrier) ----
  {
    const int kn = t >> 2, p = t & 3;   // neighbor row, channel quarter
    float vals[16];
    float d0 = 0.0f, d1 = 0.0f, d2v = 0.0f;
    if (kn < cnt) {
      int n = nbr[(size_t)cid * KK + kn];   // per-thread (4x redundant, cached)
      const float* xp = x + ((size_t)b * NN + n) * CC + p * 16;
#pragma unroll
      for (int i = 0; i < 4; ++i) {
        float4 v = ((const float4*)xp)[i];
        vals[i * 4 + 0] = v.x; vals[i * 4 + 1] = v.y;
        vals[i * 4 + 2] = v.z; vals[i * 4 + 3] = v.w;
      }
      if (p == 0) {
        const float* pp = pos + ((size_t)b * NN + n) * 3;
        float c0 = pos_s[(size_t)cid * 3 + 0];
        float c1 = pos_s[(size_t)cid * 3 + 1];
        float c2 = pos_s[(size_t)cid * 3 + 2];
        d0 = pp[0] - c0; d1 = pp[1] - c1; d2v = pp[2] - c2;
      }
    } else {
#pragma unroll
      for (int i = 0; i < 16; ++i) vals[i] = 0.0f;
    }
#pragma unroll
    for (int j = 0; j < 16; j += 2) {
      unsigned int h0, l0, h1, l1;
      split2(vals[j], h0, l0);
      split2(vals[j + 1], h1, l1);
      int c = p * 16 + j;
      *(unsigned int*)&Ah[kn * SA + c] = h0 | (h1 << 16);
      *(unsigned int*)&Al[kn * SA + c] = l0 | (l1 << 16);
    }
    if (p == 0) {
      unsigned int h0, l0, h1, l1, h2, l2;
      split2(d0, h0, l0); split2(d1, h1, l1); split2(d2v, h2, l2);
      *(unsigned int*)&Ah[kn * SA + 64] = h0 | (h1 << 16);
      *(unsigned int*)&Al[kn * SA + 64] = l0 | (l1 << 16);
      *(unsigned int*)&Ah[kn * SA + 66] = h2;        // c=67 zero
      *(unsigned int*)&Al[kn * SA + 66] = l2;
    } else if (p == 1) {
#pragma unroll
      for (int c = 68; c < 80; c += 2) {
        *(unsigned int*)&Ah[kn * SA + c] = 0u;
        *(unsigned int*)&Al[kn * SA + c] = 0u;
      }
    } else if (p == 2) {
#pragma unroll
      for (int c = 80; c < 96; c += 2) {
        *(unsigned int*)&Ah[kn * SA + c] = 0u;
        *(unsigned int*)&Al[kn * SA + c] = 0u;
      }
    }
  }
  __syncthreads();   // bar1: A-planes visible

  f32x4 acc[4][2];
#pragma unroll
  for (int mt = 0; mt < 4; ++mt)
#pragma unroll
    for (int nt = 0; nt < 2; ++nt) acc[mt][nt] = (f32x4)0.0f;

  // ---- layer 1: feat[64x96] @ W1T -> h1[64x128] ----
#pragma unroll
  for (int kc = 0; kc < 3; ++kc) {
    bf16x8 bh[2], bl[2];
#pragma unroll
    for (int nt = 0; nt < 2; ++nt) {
      int o = (wbase + nt * 16 + r) * KC1 + kc * 32 + q * 8;
      bh[nt] = *(const bf16x8*)(W1Th + o);
      bl[nt] = *(const bf16x8*)(W1Tl + o);
    }
#pragma unroll
    for (int mt = 0; mt < 4; ++mt) {
      int o = (mt * 16 + r) * SA + kc * 32 + q * 8;
      bf16x8 ah = *(const bf16x8*)&Ah[o];
      bf16x8 al = *(const bf16x8*)&Al[o];
#pragma unroll
      for (int nt = 0; nt < 2; ++nt) {
        acc[mt][nt] = __builtin_amdgcn_mfma_f32_16x16x32_bf16(ah, bh[nt], acc[mt][nt], 0, 0, 0);
        acc[mt][nt] = __builtin_amdgcn_mfma_f32_16x16x32_bf16(al, bh[nt], acc[mt][nt], 0, 0, 0);
        acc[mt][nt] = __builtin_amdgcn_mfma_f32_16x16x32_bf16(ah, bl[nt], acc[mt][nt], 0, 0, 0);
      }
    }
  }
  __syncthreads();   // bar2: all waves done READING A-planes (alias guard)

  // ---- bias + relu + split into h1 planes (overwrites A region) ----
  {
    float b1v[2] = { b1[wbase + r], b1[wbase + 16 + r] };
#pragma unroll
    for (int mt = 0; mt < 4; ++mt)
#pragma unroll
      for (int nt = 0; nt < 2; ++nt)
#pragma unroll
        for (int i = 0; i < 4; ++i) {
          int m = mt * 16 + q * 4 + i;
          int n = wbase + nt * 16 + r;
          float v = fmaxf(acc[mt][nt][i] + b1v[nt], 0.0f);
          unsigned int h, l; split2(v, h, l);
          Hh[m * SH + n] = (unsigned short)h;
          Hl[m * SH + n] = (unsigned short)l;
        }
  }
  __syncthreads();   // bar3: H-planes visible

  // ---- layer 2: h1[64x128] @ W2T ----
#pragma unroll
  for (int mt = 0; mt < 4; ++mt)
#pragma unroll
    for (int nt = 0; nt < 2; ++nt) acc[mt][nt] = (f32x4)0.0f;
#pragma unroll
  for (int kc = 0; kc < 4; ++kc) {
    bf16x8 bh[2], bl[2];
#pragma unroll
    for (int nt = 0; nt < 2; ++nt) {
      int o = (wbase + nt * 16 + r) * HH + kc * 32 + q * 8;
      bh[nt] = *(const bf16x8*)(W2Th + o);
      bl[nt] = *(const bf16x8*)(W2Tl + o);
    }
#pragma unroll
    for (int mt = 0; mt < 4; ++mt) {
      int o = (mt * 16 + r) * SH + kc * 32 + q * 8;
      bf16x8 ah = *(const bf16x8*)&Hh[o];
      bf16x8 al = *(const bf16x8*)&Hl[o];
#pragma unroll
      for (int nt = 0; nt < 2; ++nt) {
        acc[mt][nt] = __builtin_amdgcn_mfma_f32_16x16x32_bf16(ah, bh[nt], acc[mt][nt], 0, 0, 0);
        acc[mt][nt] = __builtin_amdgcn_mfma_f32_16x16x32_bf16(al, bh[nt], acc[mt][nt], 0, 0, 0);
        acc[mt][nt] = __builtin_amdgcn_mfma_f32_16x16x32_bf16(ah, bl[nt], acc[mt][nt], 0, 0, 0);
      }
    }
  }

  // ---- bias + relu + masked max over valid rows, write out ----
  {
    float b2v[2] = { b2[wbase + r], b2[wbase + 16 + r] };
#pragma unroll
    for (int nt = 0; nt < 2; ++nt) {
      float vmax = NEGV;
#pragma unroll
      for (int mt = 0; mt < 4; ++mt)
#pragma unroll
        for (int i = 0; i < 4; ++i) {
          int m = mt * 16 + q * 4 + i;
          float v = fmaxf(acc[mt][nt][i] + b2v[nt], 0.0f);
          if (m < cnt) vmax = fmaxf(vmax, v);
        }
      vmax = fmaxf(vmax, __shfl_xor(vmax, 16, 64));
      vmax = fmaxf(vmax, __shfl_xor(vmax, 32, 64));
      if (q == 0)
        out[(size_t)cid * HH + wbase + nt * 16 + r] = (cnt > 0) ? vmax : 0.0f;
    }
  }
}

// ---------------------------------------------------------------------------
extern "C" void kernel_launch(void* const* d_in, const int* in_sizes, int n_in,
                              void* d_out, int out_size, void* d_ws, size_t ws_size,
                              hipStream_t stream) {
  const float* x   = (const float*)d_in[0];
  const float* pos = (const float*)d_in[1];
  const float* W1  = (const float*)d_in[2];
  const float* b1  = (const float*)d_in[3];
  const float* W2  = (const float*)d_in[4];
  const float* b2  = (const float*)d_in[5];
  float* out = (float*)d_out;
  float* pos_s_out = out + (size_t)BB * MM * HH;

  char* ws = (char*)d_ws;
  float* pos_s_ws = (float*)(ws);                       // 196608 B
  float* pn       = (float*)(ws + 196608);              // 262144 B
  int*   nbr      = (int*)  (ws + 458752);              // 4194304 B
  int*   cnt      = (int*)  (ws + 4653056);             // 65536 B
  unsigned short* W1Th = (unsigned short*)(ws + 4718592);  // 24576 B
  unsigned short* W1Tl = (unsigned short*)(ws + 4743168);  // 24576 B
  unsigned short* W2Th = (unsigned short*)(ws + 4767744);  // 32768 B
  unsigned short* W2Tl = (unsigned short*)(ws + 4800512);  // 32768 B

  wprep_kernel<<<HH, 128, 0, stream>>>(W1, W2, W1Th, W1Tl, W2Th, W2Tl);
  fps_kernel<<<BB, FTH, 0, stream>>>(pos, pos_s_ws, pos_s_out);
  pn_kernel<<<(BB * NN) / 256, 256, 0, stream>>>(pos, pn);
  ballq_kernel<<<(BB * MM) / 4, 256, 0, stream>>>(pos, pn, pos_s_ws, nbr, cnt);
  mlp_kernel<<<BB * MM, 256, 0, stream>>>(x, pos, pos_s_ws, nbr, cnt,
                                          W1Th, W1Tl, W2Th, W2Tl, b1, b2, out);
}